// Round 3
// baseline (199.155 us; speedup 1.0000x reference)
//
#include <hip/hip_runtime.h>
#include <math.h>
#include <float.h>

#define BS 32
#define NQ 300
#define NC 2001
#define NT 25
#define KSLOT 5   // ceil(NQ/64)

// ---------------- Kernel 1: cost^T[b][t][q] = -softmax(logits[b,q,:])[targets[b,t]] ----------------
// Single global pass: row staged into registers (8 x float4 per lane), max & sum-exp from regs.
__global__ __launch_bounds__(64) void cost_kernel(const float* __restrict__ logits,
                                                  const int* __restrict__ targets,
                                                  float* __restrict__ costT) {
    int row = blockIdx.x;            // b*NQ + q
    int b = row / NQ;
    int q = row - b * NQ;
    const float* lp = logits + (size_t)row * NC;
    int lane = threadIdx.x;

    // row base elem offset = row*2001 -> misalignment cycles with row%4
    int head = (4 - (row & 3)) & 3;
    int nvec = (NC - head) >> 2;
    int tail = (NC - head) & 3;
    const float4* vp = (const float4*)(lp + head);

    float4 xr[8];
    int cnt = 0;
    for (int k = lane; k < nvec; k += 64) xr[cnt++] = vp[k];
    float hv = (lane < head) ? lp[lane] : -FLT_MAX;
    float tv = (lane < tail) ? lp[head + 4 * nvec + lane] : -FLT_MAX;

    // ---- max ----
    float m = fmaxf(hv, tv);
    for (int t = 0; t < cnt; ++t) {
        float4 x = xr[t];
        m = fmaxf(m, fmaxf(fmaxf(x.x, x.y), fmaxf(x.z, x.w)));
    }
    for (int off = 1; off < 64; off <<= 1) m = fmaxf(m, __shfl_xor(m, off));

    // ---- sum of exp ----
    float s = 0.f;
    for (int t = 0; t < cnt; ++t) {
        float4 x = xr[t];
        s += expf(x.x - m) + expf(x.y - m) + expf(x.z - m) + expf(x.w - m);
    }
    if (lane < head) s += expf(hv - m);
    if (lane < tail) s += expf(tv - m);
    for (int off = 1; off < 64; off <<= 1) s += __shfl_xor(s, off);

    if (lane < NT) {
        int t = targets[b * NT + lane];
        float p = expf(lp[t] - m) / s;
        costT[((size_t)b * NT + lane) * NQ + q] = -p;
    }
}

// ---------------- Kernel 2: Jonker-Volgenant LSAP per batch (rows=targets 25, cols=queries 300) ----
// JV init (u = row minima, greedy tight assignment) cuts Dijkstra iterations ~10x; the optimum is
// unique w.p. 1 for continuous random costs, so the final matching equals scipy's from-scratch JV.
__global__ __launch_bounds__(64) void lsap_kernel(const float* __restrict__ costT,
                                                  int* __restrict__ out) {
    int b = blockIdx.x;
    int tid = threadIdx.x;

    __shared__ float   C[NT * NQ];       // 30000 B
    __shared__ double  u[NT];
    __shared__ double  shortestS[NQ];    // published at scan time (for dual update)
    __shared__ int     pathS[NQ];        // published at scan time (for augment)
    __shared__ int     row4col[NQ];
    __shared__ int     col4row[NT];
    __shared__ int     sr_rows[NT];

    // vectorized C load: 7500 floats, batch base 30000 B -> 16B aligned
    {
        const float4* src4 = (const float4*)(costT + (size_t)b * NT * NQ);
        float4* dst4 = (float4*)C;
        for (int k = tid; k < (NT * NQ) / 4; k += 64) dst4[k] = src4[k];
    }
    for (int j = tid; j < NQ; j += 64) row4col[j] = -1;
    if (tid < NT) col4row[tid] = -1;

    double v_r[KSLOT];
    bool   own[KSLOT];
    bool   free_r[KSLOT];
    #pragma unroll
    for (int k = 0; k < KSLOT; ++k) {
        v_r[k] = 0.0;
        own[k] = (tid + 64 * k) < NQ;
        free_r[k] = own[k];
    }
    __syncthreads();

    // ---- dual init: u[i] = min_j C[i][j] (f32 min == f64 min ordering; promote exactly) ----
    if (tid < NT) {
        int base = tid * NQ;
        float m0 = FLT_MAX, m1 = FLT_MAX, m2 = FLT_MAX, m3 = FLT_MAX;
        for (int j = 0; j < NQ; j += 4) {          // NQ % 4 == 0
            m0 = fminf(m0, C[base + j]);
            m1 = fminf(m1, C[base + j + 1]);
            m2 = fminf(m2, C[base + j + 2]);
            m3 = fminf(m3, C[base + j + 3]);
        }
        u[tid] = (double)fminf(fminf(m0, m1), fminf(m2, m3));
    }
    __syncthreads();

    // ---- greedy tight assignment (v=0): row i -> lowest free j with C[i][j] == u[i] ----
    for (int i = 0; i < NT; ++i) {
        float rm = (float)u[i];                    // exact round-trip of the f32 row min
        int jm = -1;
        #pragma unroll
        for (int k = 0; k < KSLOT; ++k) {
            int j = tid + 64 * k;
            int jc = (j < NQ) ? j : (NQ - 1);      // avoid OOB read; predicate masks it
            unsigned long long mk = __ballot(free_r[k] && (C[i * NQ + jc] == rm));
            if (jm < 0 && mk) jm = 64 * k + __builtin_ctzll(mk);
        }
        if (jm >= 0) {
            if (tid == (jm & 63)) free_r[jm >> 6] = false;
            if (tid == 0) { row4col[jm] = i; col4row[i] = jm; }  // same-wave DS order: visible next i
        }
    }
    __syncthreads();

    // ---- shortest-augmenting-path for remaining free rows (identical body to the passing version) --
    for (int cur = 0; cur < NT; ++cur) {
        if (col4row[cur] != -1) continue;          // uniform read; assigned greedily

        double shortest_r[KSLOT];
        int    path_r[KSLOT];
        bool   sc_r[KSLOT];
        #pragma unroll
        for (int k = 0; k < KSLOT; ++k) { shortest_r[k] = INFINITY; path_r[k] = -1; sc_r[k] = false; }

        double minVal = 0.0;   // wave-uniform
        int i = cur;           // wave-uniform
        int nsr = 0;
        int sink = -1;

        while (sink == -1) {
            if (tid == 0) sr_rows[nsr] = i;
            nsr++;
            double ui = u[i];  // uniform LDS read (u stable during Dijkstra)

            // relax owned, unscanned columns + local min (registers only; C from LDS)
            double lmin = INFINITY;
            #pragma unroll
            for (int k = 0; k < KSLOT; ++k) {
                if (own[k] && !sc_r[k]) {
                    int j = tid + 64 * k;
                    double d = ((minVal + (double)C[i * NQ + j]) - ui) - v_r[k];
                    if (d < shortest_r[k]) { shortest_r[k] = d; path_r[k] = i; }
                    if (shortest_r[k] < lmin) lmin = shortest_r[k];
                }
            }
            // value-only f64 min butterfly
            double gmin = lmin;
            #pragma unroll
            for (int off = 1; off < 64; off <<= 1) {
                double o = __shfl_xor(gmin, off);
                if (o < gmin) gmin = o;
            }
            // lowest-column argmin via ballots (exact equality vs gmin; k-major = ascending j)
            int jpos = -1;
            #pragma unroll
            for (int k = 0; k < KSLOT; ++k) {
                unsigned long long mk =
                    __ballot(own[k] && !sc_r[k] && shortest_r[k] == gmin);
                if (jpos < 0 && mk) jpos = 64 * k + __builtin_ctzll(mk);
            }
            minVal = gmin;

            // mark scanned; publish path/shortest for the epilogue phases
            int kj = jpos >> 6, lj = jpos & 63;
            if (tid == lj) {
                sc_r[kj] = true;
                pathS[jpos] = path_r[kj];
            }
            if (tid == 0) shortestS[jpos] = gmin;

            int r = row4col[jpos];   // uniform read; stable during Dijkstra
            if (r == -1) sink = jpos; else i = r;
            __syncthreads();         // publish pathS/shortestS/sr_rows
        }

        // dual updates (rows in sr_rows are distinct; sr_rows[0] == cur)
        if (tid == 0) {
            u[cur] += minVal;
        } else if (tid < nsr) {
            int irow = sr_rows[tid];
            u[irow] += minVal - shortestS[col4row[irow]];
        }
        #pragma unroll
        for (int k = 0; k < KSLOT; ++k) {
            if (sc_r[k]) v_r[k] -= minVal - shortest_r[k];
        }
        __syncthreads();   // duals (col4row reads) done before augment rewrites col4row

        // augment along path (serial, <= NT steps)
        if (tid == 0) {
            int j = sink;
            while (true) {
                int ii = pathS[j];
                row4col[j] = ii;
                int nj = col4row[ii];
                col4row[ii] = j;
                j = nj;
                if (ii == cur) break;
            }
        }
        __syncthreads();
    }

    // epilogue: order = stable argsort(col4row); values distinct -> rank = #smaller
    if (tid < NT) {
        int myq = col4row[tid];
        int rank = 0;
        for (int k = 0; k < NT; ++k) {
            if (col4row[k] < myq) rank++;
        }
        out[b * NT + rank]           = myq;  // row_inds
        out[BS * NT + b * NT + rank] = tid;  // col_inds
    }
}

extern "C" void kernel_launch(void* const* d_in, const int* in_sizes, int n_in,
                              void* d_out, int out_size, void* d_ws, size_t ws_size,
                              hipStream_t stream) {
    const float* logits  = (const float*)d_in[0];
    const int*   targets = (const int*)d_in[1];
    int*         out     = (int*)d_out;
    float*       costT   = (float*)d_ws;   // BS*NT*NQ floats = 960000 B

    cost_kernel<<<BS * NQ, 64, 0, stream>>>(logits, targets, costT);
    lsap_kernel<<<BS, 64, 0, stream>>>(costT, out);
}

// Round 4
// 142.855 us; speedup vs baseline: 1.3941x; 1.3941x over previous
//
#include <hip/hip_runtime.h>
#include <math.h>
#include <float.h>

#define BS 32
#define NQ 300
#define NC 2001
#define NT 25
#define KSLOT 5   // ceil(NQ/64)
#define RSLOT 8   // ceil(ceil(NC/4)/64) vector slots per lane

// ---------------- Kernel 1: cost^T[b][t][q] = -softmax(logits[b,q,:])[targets[b,t]] ----------------
// Single global pass: row staged into registers (8 x float4 per lane, STATIC indexing — a dynamic
// index here lowers the array to scratch and round-trips HBM; that was round-3's 80 us regression).
__global__ __launch_bounds__(64) void cost_kernel(const float* __restrict__ logits,
                                                  const int* __restrict__ targets,
                                                  float* __restrict__ costT) {
    int row = blockIdx.x;            // b*NQ + q
    int b = row / NQ;
    int q = row - b * NQ;
    const float* lp = logits + (size_t)row * NC;
    int lane = threadIdx.x;

    // row base elem offset = row*2001 -> misalignment cycles with row%4
    int head = (4 - (row & 3)) & 3;
    int nvec = (NC - head) >> 2;     // 499 or 500
    int tail = (NC - head) & 3;
    const float4* vp = (const float4*)(lp + head);

    const float NEG = -INFINITY;     // pad: ignored by max, exp -> exactly 0
    float4 xr[RSLOT];
    #pragma unroll
    for (int t = 0; t < RSLOT; ++t) {
        int k = lane + 64 * t;
        xr[t] = (k < nvec) ? vp[k] : make_float4(NEG, NEG, NEG, NEG);
    }
    float hv = (lane < head) ? lp[lane] : NEG;
    float tv = (lane < tail) ? lp[head + 4 * nvec + lane] : NEG;

    // ---- max ----
    float m = fmaxf(hv, tv);
    #pragma unroll
    for (int t = 0; t < RSLOT; ++t) {
        float4 x = xr[t];
        m = fmaxf(m, fmaxf(fmaxf(x.x, x.y), fmaxf(x.z, x.w)));
    }
    for (int off = 1; off < 64; off <<= 1) m = fmaxf(m, __shfl_xor(m, off));

    // ---- sum of exp (pad elements contribute exactly 0) ----
    float s = expf(hv - m) + expf(tv - m);
    #pragma unroll
    for (int t = 0; t < RSLOT; ++t) {
        float4 x = xr[t];
        s += expf(x.x - m) + expf(x.y - m) + expf(x.z - m) + expf(x.w - m);
    }
    for (int off = 1; off < 64; off <<= 1) s += __shfl_xor(s, off);

    if (lane < NT) {
        int t = targets[b * NT + lane];
        float p = expf(lp[t] - m) / s;   // L1/L2 hit: row was just streamed
        costT[((size_t)b * NT + lane) * NQ + q] = -p;
    }
}

// ---------------- Kernel 2: Jonker-Volgenant LSAP per batch (rows=targets 25, cols=queries 300) ----
// JV init (u = row minima, greedy tight assignment) cuts Dijkstra iterations ~10x; the optimum is
// unique w.p. 1 for continuous random costs, so the final matching equals scipy's from-scratch JV.
__global__ __launch_bounds__(64) void lsap_kernel(const float* __restrict__ costT,
                                                  int* __restrict__ out) {
    int b = blockIdx.x;
    int tid = threadIdx.x;

    __shared__ float   C[NT * NQ];       // 30000 B
    __shared__ double  u[NT];
    __shared__ double  shortestS[NQ];    // published at scan time (for dual update)
    __shared__ int     pathS[NQ];        // published at scan time (for augment)
    __shared__ int     row4col[NQ];
    __shared__ int     col4row[NT];
    __shared__ int     sr_rows[NT];

    // vectorized C load: 7500 floats, batch base 30000 B -> 16B aligned
    {
        const float4* src4 = (const float4*)(costT + (size_t)b * NT * NQ);
        float4* dst4 = (float4*)C;
        for (int k = tid; k < (NT * NQ) / 4; k += 64) dst4[k] = src4[k];
    }
    for (int j = tid; j < NQ; j += 64) row4col[j] = -1;
    if (tid < NT) col4row[tid] = -1;

    double v_r[KSLOT];
    bool   own[KSLOT];
    bool   free_r[KSLOT];
    #pragma unroll
    for (int k = 0; k < KSLOT; ++k) {
        v_r[k] = 0.0;
        own[k] = (tid + 64 * k) < NQ;
        free_r[k] = own[k];
    }
    __syncthreads();

    // ---- dual init: u[i] = min_j C[i][j] (f32 min == f64 min ordering; promote exactly) ----
    if (tid < NT) {
        int base = tid * NQ;
        float m0 = FLT_MAX, m1 = FLT_MAX, m2 = FLT_MAX, m3 = FLT_MAX;
        for (int j = 0; j < NQ; j += 4) {          // NQ % 4 == 0
            m0 = fminf(m0, C[base + j]);
            m1 = fminf(m1, C[base + j + 1]);
            m2 = fminf(m2, C[base + j + 2]);
            m3 = fminf(m3, C[base + j + 3]);
        }
        u[tid] = (double)fminf(fminf(m0, m1), fminf(m2, m3));
    }
    __syncthreads();

    // ---- greedy tight assignment (v=0): row i -> lowest free j with C[i][j] == u[i] ----
    for (int i = 0; i < NT; ++i) {
        float rm = (float)u[i];                    // exact round-trip of the f32 row min
        int jm = -1;
        #pragma unroll
        for (int k = 0; k < KSLOT; ++k) {
            int j = tid + 64 * k;
            int jc = (j < NQ) ? j : (NQ - 1);      // avoid OOB read; predicate masks it
            unsigned long long mk = __ballot(free_r[k] && (C[i * NQ + jc] == rm));
            if (jm < 0 && mk) jm = 64 * k + __builtin_ctzll(mk);
        }
        if (jm >= 0) {
            if (tid == (jm & 63)) free_r[jm >> 6] = false;
            if (tid == 0) { row4col[jm] = i; col4row[i] = jm; }  // same-wave DS order: visible next i
        }
    }
    __syncthreads();

    // ---- shortest-augmenting-path for remaining free rows ----
    for (int cur = 0; cur < NT; ++cur) {
        if (col4row[cur] != -1) continue;          // uniform read; assigned greedily

        double shortest_r[KSLOT];
        int    path_r[KSLOT];
        bool   sc_r[KSLOT];
        #pragma unroll
        for (int k = 0; k < KSLOT; ++k) { shortest_r[k] = INFINITY; path_r[k] = -1; sc_r[k] = false; }

        double minVal = 0.0;   // wave-uniform
        int i = cur;           // wave-uniform
        int nsr = 0;
        int sink = -1;

        while (sink == -1) {
            if (tid == 0) sr_rows[nsr] = i;
            nsr++;
            double ui = u[i];  // uniform LDS read (u stable during Dijkstra)

            // relax owned, unscanned columns + local min (registers only; C from LDS)
            double lmin = INFINITY;
            #pragma unroll
            for (int k = 0; k < KSLOT; ++k) {
                if (own[k] && !sc_r[k]) {
                    int j = tid + 64 * k;
                    double d = ((minVal + (double)C[i * NQ + j]) - ui) - v_r[k];
                    if (d < shortest_r[k]) { shortest_r[k] = d; path_r[k] = i; }
                    if (shortest_r[k] < lmin) lmin = shortest_r[k];
                }
            }
            // value-only f64 min butterfly
            double gmin = lmin;
            #pragma unroll
            for (int off = 1; off < 64; off <<= 1) {
                double o = __shfl_xor(gmin, off);
                if (o < gmin) gmin = o;
            }
            // lowest-column argmin via ballots (exact equality vs gmin; k-major = ascending j)
            int jpos = -1;
            #pragma unroll
            for (int k = 0; k < KSLOT; ++k) {
                unsigned long long mk =
                    __ballot(own[k] && !sc_r[k] && shortest_r[k] == gmin);
                if (jpos < 0 && mk) jpos = 64 * k + __builtin_ctzll(mk);
            }
            minVal = gmin;

            // mark scanned; publish path/shortest for the epilogue phases
            int kj = jpos >> 6, lj = jpos & 63;
            if (tid == lj) {
                sc_r[kj] = true;
                pathS[jpos] = path_r[kj];
            }
            if (tid == 0) shortestS[jpos] = gmin;

            int r = row4col[jpos];   // uniform read; stable during Dijkstra
            if (r == -1) sink = jpos; else i = r;
            __syncthreads();         // publish pathS/shortestS/sr_rows
        }

        // dual updates (rows in sr_rows are distinct; sr_rows[0] == cur)
        if (tid == 0) {
            u[cur] += minVal;
        } else if (tid < nsr) {
            int irow = sr_rows[tid];
            u[irow] += minVal - shortestS[col4row[irow]];
        }
        #pragma unroll
        for (int k = 0; k < KSLOT; ++k) {
            if (sc_r[k]) v_r[k] -= minVal - shortest_r[k];
        }
        __syncthreads();   // duals (col4row reads) done before augment rewrites col4row

        // augment along path (serial, <= NT steps)
        if (tid == 0) {
            int j = sink;
            while (true) {
                int ii = pathS[j];
                row4col[j] = ii;
                int nj = col4row[ii];
                col4row[ii] = j;
                j = nj;
                if (ii == cur) break;
            }
        }
        __syncthreads();
    }

    // epilogue: order = stable argsort(col4row); values distinct -> rank = #smaller
    if (tid < NT) {
        int myq = col4row[tid];
        int rank = 0;
        for (int k = 0; k < NT; ++k) {
            if (col4row[k] < myq) rank++;
        }
        out[b * NT + rank]           = myq;  // row_inds
        out[BS * NT + b * NT + rank] = tid;  // col_inds
    }
}

extern "C" void kernel_launch(void* const* d_in, const int* in_sizes, int n_in,
                              void* d_out, int out_size, void* d_ws, size_t ws_size,
                              hipStream_t stream) {
    const float* logits  = (const float*)d_in[0];
    const int*   targets = (const int*)d_in[1];
    int*         out     = (int*)d_out;
    float*       costT   = (float*)d_ws;   // BS*NT*NQ floats = 960000 B

    cost_kernel<<<BS * NQ, 64, 0, stream>>>(logits, targets, costT);
    lsap_kernel<<<BS, 64, 0, stream>>>(costT, out);
}

// Round 5
// 138.359 us; speedup vs baseline: 1.4394x; 1.0325x over previous
//
#include <hip/hip_runtime.h>
#include <math.h>
#include <float.h>

#define BS 32
#define NQ 300
#define NC 2001
#define NT 25
#define KSLOT 5   // ceil(NQ/64)
#define RSLOT 8   // ceil(ceil(NC/4)/64) vector slots per lane
#define RPB 4     // rows per block (one wave each)

// ---------------- Kernel 1: costQT[b][q][t] = -softmax(logits[b,q,:])[targets[b,t]] ----------------
// One wave per row, 4 rows per 256-thread block (64-thread blocks cap at ~16 wg/CU = half occupancy).
// Row staged into registers with STATIC indexing (dynamic index -> scratch spill, round-3 lesson).
// Intermediate stored TRANSPOSED [b][q][t]: lanes 0..24 write 100 contiguous bytes (2 sectors, not 25).
__global__ __launch_bounds__(256) void cost_kernel(const float* __restrict__ logits,
                                                   const int* __restrict__ targets,
                                                   float* __restrict__ costQT) {
    int row = blockIdx.x * RPB + (threadIdx.x >> 6);   // b*NQ + q
    int b = row / NQ;
    int q = row - b * NQ;
    const float* lp = logits + (size_t)row * NC;
    int lane = threadIdx.x & 63;

    // row base elem offset = row*2001 -> misalignment cycles with row%4
    int head = (4 - (row & 3)) & 3;
    int nvec = (NC - head) >> 2;     // 499 or 500
    int tail = (NC - head) & 3;
    const float4* vp = (const float4*)(lp + head);

    const float NEG = -INFINITY;     // pad: ignored by max, exp -> exactly 0
    float4 xr[RSLOT];
    #pragma unroll
    for (int t = 0; t < RSLOT; ++t) {
        int k = lane + 64 * t;
        xr[t] = (k < nvec) ? vp[k] : make_float4(NEG, NEG, NEG, NEG);
    }
    float hv = (lane < head) ? lp[lane] : NEG;
    float tv = (lane < tail) ? lp[head + 4 * nvec + lane] : NEG;

    // ---- max ----
    float m = fmaxf(hv, tv);
    #pragma unroll
    for (int t = 0; t < RSLOT; ++t) {
        float4 x = xr[t];
        m = fmaxf(m, fmaxf(fmaxf(x.x, x.y), fmaxf(x.z, x.w)));
    }
    for (int off = 1; off < 64; off <<= 1) m = fmaxf(m, __shfl_xor(m, off));

    // ---- sum of exp (pad elements contribute exactly 0) ----
    float s = expf(hv - m) + expf(tv - m);
    #pragma unroll
    for (int t = 0; t < RSLOT; ++t) {
        float4 x = xr[t];
        s += expf(x.x - m) + expf(x.y - m) + expf(x.z - m) + expf(x.w - m);
    }
    for (int off = 1; off < 64; off <<= 1) s += __shfl_xor(s, off);

    if (lane < NT) {
        int t = targets[b * NT + lane];
        float p = expf(lp[t] - m) / s;   // cache hit: row was just streamed
        costQT[((size_t)b * NQ + q) * NT + lane] = -p;   // contiguous 100B per wave
    }
}

// ---------------- Kernel 2: Jonker-Volgenant LSAP per batch (rows=targets 25, cols=queries 300) ----
// JV init (u = row minima, greedy tight assignment) cuts Dijkstra iterations ~10x; the optimum is
// unique w.p. 1 for continuous random costs, so the final matching equals scipy's from-scratch JV.
__global__ __launch_bounds__(64) void lsap_kernel(const float* __restrict__ costQT,
                                                  int* __restrict__ out) {
    int b = blockIdx.x;
    int tid = threadIdx.x;

    __shared__ float   C[NT * NQ];       // C[t][q], 30000 B
    __shared__ double  u[NT];
    __shared__ double  shortestS[NQ];    // published at scan time (for dual update)
    __shared__ int     pathS[NQ];        // published at scan time (for augment)
    __shared__ int     row4col[NQ];
    __shared__ int     col4row[NT];
    __shared__ int     sr_rows[NT];

    // transposing load: global [q][t] -> LDS [t][q]; coalesced reads, ~30 KB from L2
    {
        const float* src = costQT + (size_t)b * NQ * NT;
        for (int k = tid; k < NQ * NT; k += 64) {
            int q = k / NT;
            int t = k - q * NT;
            C[t * NQ + q] = src[k];
        }
    }
    for (int j = tid; j < NQ; j += 64) row4col[j] = -1;
    if (tid < NT) col4row[tid] = -1;

    double v_r[KSLOT];
    bool   own[KSLOT];
    bool   free_r[KSLOT];
    #pragma unroll
    for (int k = 0; k < KSLOT; ++k) {
        v_r[k] = 0.0;
        own[k] = (tid + 64 * k) < NQ;
        free_r[k] = own[k];
    }
    __syncthreads();

    // ---- dual init: u[i] = min_j C[i][j] (f32 min == f64 min ordering; promote exactly) ----
    if (tid < NT) {
        int base = tid * NQ;
        float m0 = FLT_MAX, m1 = FLT_MAX, m2 = FLT_MAX, m3 = FLT_MAX;
        for (int j = 0; j < NQ; j += 4) {          // NQ % 4 == 0
            m0 = fminf(m0, C[base + j]);
            m1 = fminf(m1, C[base + j + 1]);
            m2 = fminf(m2, C[base + j + 2]);
            m3 = fminf(m3, C[base + j + 3]);
        }
        u[tid] = (double)fminf(fminf(m0, m1), fminf(m2, m3));
    }
    __syncthreads();

    // ---- greedy tight assignment (v=0): row i -> lowest free j with C[i][j] == u[i] ----
    for (int i = 0; i < NT; ++i) {
        float rm = (float)u[i];                    // exact round-trip of the f32 row min
        int jm = -1;
        #pragma unroll
        for (int k = 0; k < KSLOT; ++k) {
            int j = tid + 64 * k;
            int jc = (j < NQ) ? j : (NQ - 1);      // avoid OOB read; predicate masks it
            unsigned long long mk = __ballot(free_r[k] && (C[i * NQ + jc] == rm));
            if (jm < 0 && mk) jm = 64 * k + __builtin_ctzll(mk);
        }
        if (jm >= 0) {
            if (tid == (jm & 63)) free_r[jm >> 6] = false;
            if (tid == 0) { row4col[jm] = i; col4row[i] = jm; }  // same-wave DS order: visible next i
        }
    }
    __syncthreads();

    // ---- shortest-augmenting-path for remaining free rows ----
    for (int cur = 0; cur < NT; ++cur) {
        if (col4row[cur] != -1) continue;          // uniform read; assigned greedily

        double shortest_r[KSLOT];
        int    path_r[KSLOT];
        bool   sc_r[KSLOT];
        #pragma unroll
        for (int k = 0; k < KSLOT; ++k) { shortest_r[k] = INFINITY; path_r[k] = -1; sc_r[k] = false; }

        double minVal = 0.0;   // wave-uniform
        int i = cur;           // wave-uniform
        int nsr = 0;
        int sink = -1;

        while (sink == -1) {
            if (tid == 0) sr_rows[nsr] = i;
            nsr++;
            double ui = u[i];  // uniform LDS read (u stable during Dijkstra)

            // relax owned, unscanned columns + local min (registers only; C from LDS)
            double lmin = INFINITY;
            #pragma unroll
            for (int k = 0; k < KSLOT; ++k) {
                if (own[k] && !sc_r[k]) {
                    int j = tid + 64 * k;
                    double d = ((minVal + (double)C[i * NQ + j]) - ui) - v_r[k];
                    if (d < shortest_r[k]) { shortest_r[k] = d; path_r[k] = i; }
                    if (shortest_r[k] < lmin) lmin = shortest_r[k];
                }
            }
            // value-only f64 min butterfly
            double gmin = lmin;
            #pragma unroll
            for (int off = 1; off < 64; off <<= 1) {
                double o = __shfl_xor(gmin, off);
                if (o < gmin) gmin = o;
            }
            // lowest-column argmin via ballots (exact equality vs gmin; k-major = ascending j)
            int jpos = -1;
            #pragma unroll
            for (int k = 0; k < KSLOT; ++k) {
                unsigned long long mk =
                    __ballot(own[k] && !sc_r[k] && shortest_r[k] == gmin);
                if (jpos < 0 && mk) jpos = 64 * k + __builtin_ctzll(mk);
            }
            minVal = gmin;

            // mark scanned; publish path/shortest for the epilogue phases
            int kj = jpos >> 6, lj = jpos & 63;
            if (tid == lj) {
                sc_r[kj] = true;
                pathS[jpos] = path_r[kj];
            }
            if (tid == 0) shortestS[jpos] = gmin;

            int r = row4col[jpos];   // uniform read; stable during Dijkstra
            if (r == -1) sink = jpos; else i = r;
            __syncthreads();         // publish pathS/shortestS/sr_rows
        }

        // dual updates (rows in sr_rows are distinct; sr_rows[0] == cur)
        if (tid == 0) {
            u[cur] += minVal;
        } else if (tid < nsr) {
            int irow = sr_rows[tid];
            u[irow] += minVal - shortestS[col4row[irow]];
        }
        #pragma unroll
        for (int k = 0; k < KSLOT; ++k) {
            if (sc_r[k]) v_r[k] -= minVal - shortest_r[k];
        }
        __syncthreads();   // duals (col4row reads) done before augment rewrites col4row

        // augment along path (serial, <= NT steps)
        if (tid == 0) {
            int j = sink;
            while (true) {
                int ii = pathS[j];
                row4col[j] = ii;
                int nj = col4row[ii];
                col4row[ii] = j;
                j = nj;
                if (ii == cur) break;
            }
        }
        __syncthreads();
    }

    // epilogue: order = stable argsort(col4row); values distinct -> rank = #smaller
    if (tid < NT) {
        int myq = col4row[tid];
        int rank = 0;
        for (int k = 0; k < NT; ++k) {
            if (col4row[k] < myq) rank++;
        }
        out[b * NT + rank]           = myq;  // row_inds
        out[BS * NT + b * NT + rank] = tid;  // col_inds
    }
}

extern "C" void kernel_launch(void* const* d_in, const int* in_sizes, int n_in,
                              void* d_out, int out_size, void* d_ws, size_t ws_size,
                              hipStream_t stream) {
    const float* logits  = (const float*)d_in[0];
    const int*   targets = (const int*)d_in[1];
    int*         out     = (int*)d_out;
    float*       costQT  = (float*)d_ws;   // BS*NQ*NT floats = 960000 B

    cost_kernel<<<(BS * NQ) / RPB, 256, 0, stream>>>(logits, targets, costQT);
    lsap_kernel<<<BS, 64, 0, stream>>>(costQT, out);
}